// Round 2
// baseline (416.295 us; speedup 1.0000x reference)
//
#include <hip/hip_runtime.h>

#define A_TOT 33600
#define BSZ 16
#define NMAX 32
#define NCLS 80

// flat float32 output offsets (elements), in reference return order
#define LAB_OFF 0                    // (16,33600)
#define BOX_OFF 537600               // (16,33600,4)
#define SC_OFF  2688000              // (16,33600,80)
#define POS_OFF 45696000             // (16,33600)
#define OUT_END 46233600

__device__ __forceinline__ float iou_box(const float4 p, const float4 q) {
    // matches reference: a=p, b=q; denom = (area_p + area_q) - inter + 1e-9
    float ltx = fmaxf(p.x, q.x), lty = fmaxf(p.y, q.y);
    float rbx = fminf(p.z, q.z), rby = fminf(p.w, q.w);
    float w = fmaxf(rbx - ltx, 0.0f), h = fmaxf(rby - lty, 0.0f);
    float inter = w * h;
    float ap = (p.z - p.x) * (p.w - p.y);
    float aq = (q.z - q.x) * (q.w - q.y);
    return inter / (ap + aq - inter + 1e-9f);
}

// K1: per (b,g), per level: select 9 smallest center-distances (tie -> lower idx),
// set bit g in mask[b][anchor] via atomicOr.
__global__ __launch_bounds__(256) void k_topk(const float4* __restrict__ anc,
        const float4* __restrict__ gtb, const float* __restrict__ mgt,
        unsigned int* __restrict__ mask) {
    const int bg = blockIdx.x;            // b*32+g
    const int b = bg >> 5, g = bg & 31;
    const int tid = threadIdx.x;
    const int lane = tid & 63, wv = tid >> 6;
    const float4 G = gtb[bg];
    const float gcx = (G.x + G.z) * 0.5f, gcy = (G.y + G.w) * 0.5f;
    const float m = mgt[bg];
    const unsigned int bitg = 1u << g;
    unsigned int* mrow = mask + (size_t)b * A_TOT;
    __shared__ float sd[4];
    __shared__ int   si[4];
    const int starts[3] = {0, 25600, 32000};
    const int lens[3]   = {25600, 6400, 1600};
    for (int lv = 0; lv < 3; ++lv) {
        // register-resident sorted top-9 (static indexing only)
        float d[9]; int id[9];
#pragma unroll
        for (int j = 0; j < 9; ++j) { d[j] = INFINITY; id[j] = 0x7fffffff; }
        const int st = starts[lv], en = st + lens[lv];
        for (int i = st + tid; i < en; i += 256) {
            const float4 a4 = anc[i];
            const float acx = (a4.x + a4.z) * 0.5f, acy = (a4.y + a4.w) * 0.5f;
            const float dx = gcx - acx, dy = gcy - acy;
            float nd = sqrtf(dx * dx + dy * dy) * m;
            int ni = i;
            if (nd < d[8] || (nd == d[8] && ni < id[8])) {
#pragma unroll
                for (int j = 0; j < 9; ++j) {
                    bool lt = (nd < d[j]) || (nd == d[j] && ni < id[j]);
                    if (lt) {
                        float td = d[j]; d[j] = nd; nd = td;
                        int ti = id[j]; id[j] = ni; ni = ti;
                    }
                }
            }
        }
        // 9 selection rounds: block-wide lexicographic min of per-thread heads
        for (int k = 0; k < 9; ++k) {
            const float pd_ = d[0];
            const int pi_ = id[0];
            float rd = pd_; int ri = pi_;
#pragma unroll
            for (int off = 32; off > 0; off >>= 1) {
                float od = __shfl_down(rd, off);
                int oi = __shfl_down(ri, off);
                if (od < rd || (od == rd && oi < ri)) { rd = od; ri = oi; }
            }
            if (lane == 0) { sd[wv] = rd; si[wv] = ri; }
            __syncthreads();
            float wd = sd[0]; int wi = si[0];
#pragma unroll
            for (int w2 = 1; w2 < 4; ++w2) {
                float od = sd[w2]; int oi = si[w2];
                if (od < wd || (od == wd && oi < wi)) { wd = od; wi = oi; }
            }
            __syncthreads();   // all threads done reading sd/si before next round writes
            if (pi_ == wi && wi != 0x7fffffff) {   // unique winner (anchor indices unique)
                atomicOr(mrow + wi, bitg);
#pragma unroll
                for (int j = 0; j < 8; ++j) { d[j] = d[j + 1]; id[j] = id[j + 1]; }
                d[8] = INFINITY; id[8] = 0x7fffffff;
            }
        }
    }
}

// K2: resolve multi-assigned anchors -> single bit = argmax-IoU gt (first max).
__global__ __launch_bounds__(256) void k_multi(const float4* __restrict__ anc,
        const float4* __restrict__ gtb, unsigned int* __restrict__ mask) {
    const int idx = blockIdx.x * 256 + threadIdx.x;
    if (idx >= BSZ * A_TOT) return;
    unsigned int m = mask[idx];
    if (__popc(m) > 1) {
        const int b = idx / A_TOT;
        const int a = idx - b * A_TOT;
        const float4 A4 = anc[a];
        const float4* gr = gtb + b * NMAX;
        float bestv = -1.0f; int bestg = 0;
        for (int g = 0; g < NMAX; ++g) {
            float v = iou_box(gr[g], A4);       // overlaps: iou(gt, anc)
            if (v > bestv) { bestv = v; bestg = g; }
        }
        mask[idx] = 1u << bestg;
    }
}

// K3: per (b,g) threshold = sum/count + sqrt((sum2 - sum^2/A)/(A-1)), double, deterministic.
__global__ __launch_bounds__(256) void k_thresh(const float4* __restrict__ anc,
        const float4* __restrict__ gtb, const unsigned int* __restrict__ mask,
        double* __restrict__ thr) {
    const int bg = blockIdx.x;
    const int b = bg >> 5;
    const unsigned int bitg = 1u << (bg & 31);
    const unsigned int* mrow = mask + (size_t)b * A_TOT;
    const float4 G = gtb[bg];
    double s = 0.0, s2 = 0.0; int c = 0;
    for (int a = threadIdx.x; a < A_TOT; a += 256) {
        if (mrow[a] & bitg) {
            float v = iou_box(G, anc[a]);
            s += (double)v; s2 += (double)v * (double)v; ++c;
        }
    }
    const int lane = threadIdx.x & 63, wv = threadIdx.x >> 6;
#pragma unroll
    for (int off = 32; off > 0; off >>= 1) {
        s  += __shfl_down(s, off);
        s2 += __shfl_down(s2, off);
        c  += __shfl_down(c, off);
    }
    __shared__ double ss[4], ss2[4];
    __shared__ int sc[4];
    if (lane == 0) { ss[wv] = s; ss2[wv] = s2; sc[wv] = c; }
    __syncthreads();
    if (threadIdx.x == 0) {
        double S = ss[0] + ss[1] + ss[2] + ss[3];
        double S2 = ss2[0] + ss2[1] + ss2[2] + ss2[3];
        int C = sc[0] + sc[1] + sc[2] + sc[3];
        double t;
        if (C == 0) t = 1e300;                 // reference: 0/0 -> NaN -> compare false
        else {
            double var = (S2 - S * S / (double)A_TOT) / (double)(A_TOT - 1);
            if (var < 0.0) var = 0.0;
            t = S / (double)C + sqrt(var);
        }
        thr[bg] = t;
    }
}

// K4: final outputs per (b,a). Scores/pos zero-filled by memset; only positives written.
__global__ __launch_bounds__(256) void k_out(const float4* __restrict__ anc,
        const float4* __restrict__ gtb, const int* __restrict__ glab,
        const float* __restrict__ mgt, const float4* __restrict__ pd,
        const unsigned int* __restrict__ mask, const double* __restrict__ thr,
        float* __restrict__ out) {
    const int idx = blockIdx.x * 256 + threadIdx.x;
    if (idx >= BSZ * A_TOT) return;
    const int b = idx / A_TOT;
    const int a = idx - b * A_TOT;
    const unsigned int m = mask[idx];     // popcount <= 1 after K2
    bool keep = false; int g = 0;
    if (m) {
        g = __ffs(m) - 1;
        const float v = iou_box(gtb[b * NMAX + g], anc[a]);
        keep = ((double)v > thr[b * NMAX + g]) && (mgt[b * NMAX + g] != 0.0f);
    }
    const int ag = keep ? g : 0;          // argmax of all-zero cid -> 0
    const int lab = keep ? glab[b * NMAX + ag] : NCLS;
    out[LAB_OFF + idx] = (float)lab;
    *(float4*)(out + BOX_OFF + (size_t)idx * 4) = gtb[b * NMAX + ag];
    if (keep) {
        out[POS_OFF + idx] = 1.0f;
        const float4 P = pd[idx];
        const float4* gr = gtb + b * NMAX;
        float mx = -INFINITY;
        for (int g2 = 0; g2 < NMAX; ++g2) mx = fmaxf(mx, iou_box(P, gr[g2]));  // iou(pd, gt)
        out[SC_OFF + (size_t)idx * NCLS + lab] = mx;
    }
}

extern "C" void kernel_launch(void* const* d_in, const int* in_sizes, int n_in,
                              void* d_out, int out_size, void* d_ws, size_t ws_size,
                              hipStream_t stream) {
    const float4* anc = (const float4*)d_in[0];
    // d_in[1] = n_level_bboxes (constant [25600,6400,1600]) — hardcoded
    const int*    glab = (const int*)d_in[2];
    const float4* gtb  = (const float4*)d_in[3];
    const float*  mgt  = (const float*)d_in[4];
    const float4* pd   = (const float4*)d_in[5];
    float* out = (float*)d_out;

    unsigned int* mask = (unsigned int*)d_ws;                       // 16*33600 u32 = 2.15 MB
    double* thr = (double*)((char*)d_ws + (size_t)BSZ * A_TOT * 4); // 512 doubles

    hipMemsetAsync(mask, 0, (size_t)BSZ * A_TOT * 4, stream);
    // labels+boxes regions are fully written by k_out; zero only scores+pos (contiguous)
    hipMemsetAsync(out + SC_OFF, 0, (size_t)(OUT_END - SC_OFF) * 4, stream);

    k_topk  <<<BSZ * NMAX, 256, 0, stream>>>(anc, gtb, mgt, mask);
    k_multi <<<(BSZ * A_TOT + 255) / 256, 256, 0, stream>>>(anc, gtb, mask);
    k_thresh<<<BSZ * NMAX, 256, 0, stream>>>(anc, gtb, mask, thr);
    k_out   <<<(BSZ * A_TOT + 255) / 256, 256, 0, stream>>>(anc, gtb, glab, mgt, pd, mask, thr, out);
}

// Round 3
// 320.271 us; speedup vs baseline: 1.2998x; 1.2998x over previous
//
#include <hip/hip_runtime.h>

#define A_TOT 33600
#define BSZ 16
#define NMAX 32
#define NCLS 80

// flat float32 output offsets (elements), in reference return order
#define LAB_OFF 0                    // (16,33600)
#define BOX_OFF 537600               // (16,33600,4)
#define SC_OFF  2688000              // (16,33600,80)
#define POS_OFF 45696000             // (16,33600)
#define OUT_END 46233600

// top-k decomposition: 21 waves per (b,g); each wave scans a 1600-anchor slice
// waves 0..15 -> level0 (25600), 16..19 -> level1 (6400), 20 -> level2 (1600)
#define WPG 21
#define SLICE 1600
#define CAND_PER_BG (WPG * 9)        // 189 u64 keys

__device__ __forceinline__ float iou_box(const float4 p, const float4 q) {
    float ltx = fmaxf(p.x, q.x), lty = fmaxf(p.y, q.y);
    float rbx = fminf(p.z, q.z), rby = fminf(p.w, q.w);
    float w = fmaxf(rbx - ltx, 0.0f), h = fmaxf(rby - lty, 0.0f);
    float inter = w * h;
    float ap = (p.z - p.x) * (p.w - p.y);
    float aq = (q.z - q.x) * (q.w - q.y);
    return inter / (ap + aq - inter + 1e-9f);
}

// K1a: per (b,g,slice): wave-local top-9 by key=(fbits(dist)<<32)|idx, no barriers.
__global__ __launch_bounds__(256) void k_topk_part(const float4* __restrict__ anc,
        const float4* __restrict__ gtb, const float* __restrict__ mgt,
        unsigned long long* __restrict__ part) {
    const int w = blockIdx.x * 4 + (threadIdx.x >> 6);   // global wave id
    const int lane = threadIdx.x & 63;
    const int bg = w / WPG;
    const int wl = w - bg * WPG;
    const float4 G = gtb[bg];
    const float gcx = (G.x + G.z) * 0.5f, gcy = (G.y + G.w) * 0.5f;
    const float m = mgt[bg];
    // slice base: uniform 1600-anchor slices tile [0,25600) ∪ [25600,32000) ∪ [32000,33600)
    const int base = wl * SLICE;     // contiguous across levels by construction
    unsigned long long keys[9];
#pragma unroll
    for (int j = 0; j < 9; ++j) keys[j] = ~0ull;
    for (int t = 0; t < SLICE / 64; ++t) {
        const int i = base + lane + t * 64;
        const float4 a4 = anc[i];
        const float acx = (a4.x + a4.z) * 0.5f, acy = (a4.y + a4.w) * 0.5f;
        const float dx = gcx - acx, dy = gcy - acy;
        const float nd = sqrtf(dx * dx + dy * dy) * m;   // same arithmetic as before
        unsigned long long nk = ((unsigned long long)__float_as_uint(nd) << 32)
                              | (unsigned int)i;
        if (nk < keys[8]) {
#pragma unroll
            for (int j = 0; j < 9; ++j) {
                if (nk < keys[j]) {
                    unsigned long long t2 = keys[j]; keys[j] = nk; nk = t2;
                }
            }
        }
    }
    // 9 intra-wave selection rounds: butterfly min, owner pops, lane k stores
    unsigned long long* dst = part + (size_t)w * 9;
    for (int k = 0; k < 9; ++k) {
        unsigned long long mn = keys[0];
#pragma unroll
        for (int off = 1; off < 64; off <<= 1) {
            unsigned long long o = __shfl_xor(mn, off);
            if (o < mn) mn = o;
        }
        if (lane == k) dst[k] = mn;
        if (keys[0] == mn) {       // unique owner (keys globally unique)
#pragma unroll
            for (int j = 0; j < 8; ++j) keys[j] = keys[j + 1];
            keys[8] = ~0ull;
        }
    }
}

// K1b: per (b,g,level): merge the per-slice candidates -> final top-9, atomicOr bit g.
__global__ __launch_bounds__(256) void k_topk_merge(const unsigned long long* __restrict__ part,
        unsigned int* __restrict__ mask) {
    const int w = blockIdx.x * 4 + (threadIdx.x >> 6);   // (bg, level) pair id
    if (w >= BSZ * NMAX * 3) return;
    const int lane = threadIdx.x & 63;
    const int bg = w / 3;
    const int lv = w - bg * 3;
    const int b = bg >> 5, g = bg & 31;
    const int cnt  = (lv == 0) ? 144 : (lv == 1) ? 36 : 9;
    const int coff = (lv == 0) ? 0   : (lv == 1) ? 144 : 180;
    const unsigned long long* src = part + (size_t)bg * CAND_PER_BG + coff;
    unsigned long long keys[3];
#pragma unroll
    for (int t = 0; t < 3; ++t) {
        const int i = lane + t * 64;
        unsigned long long nk = (i < cnt) ? src[i] : ~0ull;
        // insertion into sorted-3 (static)
#pragma unroll
        for (int j = 0; j <= t; ++j) {
            if (nk < keys[j] || j == t) {
                if (j == t) { keys[j] = nk; }
                else { unsigned long long t2 = keys[j]; keys[j] = nk; nk = t2; }
            }
        }
    }
    unsigned int* mrow = mask + (size_t)b * A_TOT;
    const unsigned int bitg = 1u << g;
    for (int k = 0; k < 9; ++k) {
        unsigned long long mn = keys[0];
#pragma unroll
        for (int off = 1; off < 64; off <<= 1) {
            unsigned long long o = __shfl_xor(mn, off);
            if (o < mn) mn = o;
        }
        if (lane == k) atomicOr(mrow + (unsigned int)(mn & 0xffffffffu), bitg);
        if (keys[0] == mn) {
            keys[0] = keys[1]; keys[1] = keys[2]; keys[2] = ~0ull;
        }
    }
}

// K2: resolve multi-assigned anchors -> single bit = argmax-IoU gt (first max).
__global__ __launch_bounds__(256) void k_multi(const float4* __restrict__ anc,
        const float4* __restrict__ gtb, unsigned int* __restrict__ mask) {
    const int idx = blockIdx.x * 256 + threadIdx.x;
    if (idx >= BSZ * A_TOT) return;
    unsigned int m = mask[idx];
    if (__popc(m) > 1) {
        const int b = idx / A_TOT;
        const int a = idx - b * A_TOT;
        const float4 A4 = anc[a];
        const float4* gr = gtb + b * NMAX;
        float bestv = -1.0f; int bestg = 0;
        for (int g = 0; g < NMAX; ++g) {
            float v = iou_box(gr[g], A4);
            if (v > bestv) { bestv = v; bestg = g; }
        }
        mask[idx] = 1u << bestg;
    }
}

// K3: per (b,g) threshold = sum/count + sqrt((sum2 - sum^2/A)/(A-1)), double, deterministic.
__global__ __launch_bounds__(256) void k_thresh(const float4* __restrict__ anc,
        const float4* __restrict__ gtb, const unsigned int* __restrict__ mask,
        double* __restrict__ thr) {
    const int bg = blockIdx.x;
    const int b = bg >> 5;
    const unsigned int bitg = 1u << (bg & 31);
    const unsigned int* mrow = mask + (size_t)b * A_TOT;
    const float4 G = gtb[bg];
    double s = 0.0, s2 = 0.0; int c = 0;
    for (int a = threadIdx.x; a < A_TOT; a += 256) {
        if (mrow[a] & bitg) {
            float v = iou_box(G, anc[a]);
            s += (double)v; s2 += (double)v * (double)v; ++c;
        }
    }
    const int lane = threadIdx.x & 63, wv = threadIdx.x >> 6;
#pragma unroll
    for (int off = 32; off > 0; off >>= 1) {
        s  += __shfl_down(s, off);
        s2 += __shfl_down(s2, off);
        c  += __shfl_down(c, off);
    }
    __shared__ double ss[4], ss2[4];
    __shared__ int sc[4];
    if (lane == 0) { ss[wv] = s; ss2[wv] = s2; sc[wv] = c; }
    __syncthreads();
    if (threadIdx.x == 0) {
        double S = ss[0] + ss[1] + ss[2] + ss[3];
        double S2 = ss2[0] + ss2[1] + ss2[2] + ss2[3];
        int C = sc[0] + sc[1] + sc[2] + sc[3];
        double t;
        if (C == 0) t = 1e300;
        else {
            double var = (S2 - S * S / (double)A_TOT) / (double)(A_TOT - 1);
            if (var < 0.0) var = 0.0;
            t = S / (double)C + sqrt(var);
        }
        thr[bg] = t;
    }
}

// K4: final outputs per (b,a). Scores/pos zero-filled by memset; only positives written.
__global__ __launch_bounds__(256) void k_out(const float4* __restrict__ anc,
        const float4* __restrict__ gtb, const int* __restrict__ glab,
        const float* __restrict__ mgt, const float4* __restrict__ pd,
        const unsigned int* __restrict__ mask, const double* __restrict__ thr,
        float* __restrict__ out) {
    const int idx = blockIdx.x * 256 + threadIdx.x;
    if (idx >= BSZ * A_TOT) return;
    const int b = idx / A_TOT;
    const int a = idx - b * A_TOT;
    const unsigned int m = mask[idx];
    bool keep = false; int g = 0;
    if (m) {
        g = __ffs(m) - 1;
        const float v = iou_box(gtb[b * NMAX + g], anc[a]);
        keep = ((double)v > thr[b * NMAX + g]) && (mgt[b * NMAX + g] != 0.0f);
    }
    const int ag = keep ? g : 0;
    const int lab = keep ? glab[b * NMAX + ag] : NCLS;
    out[LAB_OFF + idx] = (float)lab;
    *(float4*)(out + BOX_OFF + (size_t)idx * 4) = gtb[b * NMAX + ag];
    if (keep) {
        out[POS_OFF + idx] = 1.0f;
        const float4 P = pd[idx];
        const float4* gr = gtb + b * NMAX;
        float mx = -INFINITY;
        for (int g2 = 0; g2 < NMAX; ++g2) mx = fmaxf(mx, iou_box(P, gr[g2]));
        out[SC_OFF + (size_t)idx * NCLS + lab] = mx;
    }
}

extern "C" void kernel_launch(void* const* d_in, const int* in_sizes, int n_in,
                              void* d_out, int out_size, void* d_ws, size_t ws_size,
                              hipStream_t stream) {
    const float4* anc = (const float4*)d_in[0];
    const int*    glab = (const int*)d_in[2];
    const float4* gtb  = (const float4*)d_in[3];
    const float*  mgt  = (const float*)d_in[4];
    const float4* pd   = (const float4*)d_in[5];
    float* out = (float*)d_out;

    // workspace layout
    unsigned int* mask = (unsigned int*)d_ws;                              // 2,150,400 B
    double* thr = (double*)((char*)d_ws + 2150400);                        //     4,096 B
    unsigned long long* part = (unsigned long long*)((char*)d_ws + 2154496); // 774,144 B

    hipMemsetAsync(mask, 0, (size_t)BSZ * A_TOT * 4, stream);
    hipMemsetAsync(out + SC_OFF, 0, (size_t)(OUT_END - SC_OFF) * 4, stream);

    // top-k: 512*21 waves = 2688 blocks of 4 waves; merge: 512*3 waves = 384 blocks
    k_topk_part <<<BSZ * NMAX * WPG / 4, 256, 0, stream>>>(anc, gtb, mgt, part);
    k_topk_merge<<<BSZ * NMAX * 3 / 4, 256, 0, stream>>>(part, mask);
    k_multi <<<(BSZ * A_TOT + 255) / 256, 256, 0, stream>>>(anc, gtb, mask);
    k_thresh<<<BSZ * NMAX, 256, 0, stream>>>(anc, gtb, mask, thr);
    k_out   <<<(BSZ * A_TOT + 255) / 256, 256, 0, stream>>>(anc, gtb, glab, mgt, pd, mask, thr, out);
}

// Round 4
// 309.585 us; speedup vs baseline: 1.3447x; 1.0345x over previous
//
#include <hip/hip_runtime.h>

#define A_TOT 33600
#define BSZ 16
#define NMAX 32
#define NCLS 80

// flat float32 output offsets (elements), in reference return order
#define LAB_OFF 0                    // (16,33600)
#define BOX_OFF 537600               // (16,33600,4)
#define SC_OFF  2688000              // (16,33600,80)
#define POS_OFF 45696000             // (16,33600)
#define OUT_END 46233600

// top-k decomposition: 21 waves per (b,g); each wave scans a 1600-anchor slice
#define WPG 21
#define SLICE 1600
#define CAND_PER_BG (WPG * 9)        // 189 u64 keys

__device__ __forceinline__ float iou_box(const float4 p, const float4 q) {
    float ltx = fmaxf(p.x, q.x), lty = fmaxf(p.y, q.y);
    float rbx = fminf(p.z, q.z), rby = fminf(p.w, q.w);
    float w = fmaxf(rbx - ltx, 0.0f), h = fmaxf(rby - lty, 0.0f);
    float inter = w * h;
    float ap = (p.z - p.x) * (p.w - p.y);
    float aq = (q.z - q.x) * (q.w - q.y);
    return inter / (ap + aq - inter + 1e-9f);
}

// K1a: per (b,g,slice): wave-local top-9 by key=(fbits(dist)<<32)|idx, no barriers.
__global__ __launch_bounds__(256) void k_topk_part(const float4* __restrict__ anc,
        const float4* __restrict__ gtb, const float* __restrict__ mgt,
        unsigned long long* __restrict__ part) {
    const int w = blockIdx.x * 4 + (threadIdx.x >> 6);   // global wave id
    const int lane = threadIdx.x & 63;
    const int bg = w / WPG;
    const int wl = w - bg * WPG;
    const float4 G = gtb[bg];
    const float gcx = (G.x + G.z) * 0.5f, gcy = (G.y + G.w) * 0.5f;
    const float m = mgt[bg];
    const int base = wl * SLICE;
    unsigned long long keys[9];
#pragma unroll
    for (int j = 0; j < 9; ++j) keys[j] = ~0ull;
    for (int t = 0; t < SLICE / 64; ++t) {
        const int i = base + lane + t * 64;
        const float4 a4 = anc[i];
        const float acx = (a4.x + a4.z) * 0.5f, acy = (a4.y + a4.w) * 0.5f;
        const float dx = gcx - acx, dy = gcy - acy;
        const float nd = sqrtf(dx * dx + dy * dy) * m;
        unsigned long long nk = ((unsigned long long)__float_as_uint(nd) << 32)
                              | (unsigned int)i;
        if (nk < keys[8]) {
#pragma unroll
            for (int j = 0; j < 9; ++j) {
                if (nk < keys[j]) {
                    unsigned long long t2 = keys[j]; keys[j] = nk; nk = t2;
                }
            }
        }
    }
    unsigned long long* dst = part + (size_t)w * 9;
    for (int k = 0; k < 9; ++k) {
        unsigned long long mn = keys[0];
#pragma unroll
        for (int off = 1; off < 64; off <<= 1) {
            unsigned long long o = __shfl_xor(mn, off);
            if (o < mn) mn = o;
        }
        if (lane == k) dst[k] = mn;
        if (keys[0] == mn) {
#pragma unroll
            for (int j = 0; j < 8; ++j) keys[j] = keys[j + 1];
            keys[8] = ~0ull;
        }
    }
}

// K1b: per (b,g,level): merge the per-slice candidates -> final top-9, atomicOr bit g.
__global__ __launch_bounds__(256) void k_topk_merge(const unsigned long long* __restrict__ part,
        unsigned int* __restrict__ mask) {
    const int w = blockIdx.x * 4 + (threadIdx.x >> 6);   // (bg, level) pair id
    if (w >= BSZ * NMAX * 3) return;
    const int lane = threadIdx.x & 63;
    const int bg = w / 3;
    const int lv = w - bg * 3;
    const int b = bg >> 5, g = bg & 31;
    const int cnt  = (lv == 0) ? 144 : (lv == 1) ? 36 : 9;
    const int coff = (lv == 0) ? 0   : (lv == 1) ? 144 : 180;
    const unsigned long long* src = part + (size_t)bg * CAND_PER_BG + coff;
    unsigned long long keys[3];
#pragma unroll
    for (int t = 0; t < 3; ++t) {
        const int i = lane + t * 64;
        unsigned long long nk = (i < cnt) ? src[i] : ~0ull;
#pragma unroll
        for (int j = 0; j <= t; ++j) {
            if (nk < keys[j] || j == t) {
                if (j == t) { keys[j] = nk; }
                else { unsigned long long t2 = keys[j]; keys[j] = nk; nk = t2; }
            }
        }
    }
    unsigned int* mrow = mask + (size_t)b * A_TOT;
    const unsigned int bitg = 1u << g;
    for (int k = 0; k < 9; ++k) {
        unsigned long long mn = keys[0];
#pragma unroll
        for (int off = 1; off < 64; off <<= 1) {
            unsigned long long o = __shfl_xor(mn, off);
            if (o < mn) mn = o;
        }
        if (lane == k) atomicOr(mrow + (unsigned int)(mn & 0xffffffffu), bitg);
        if (keys[0] == mn) {
            keys[0] = keys[1]; keys[1] = keys[2]; keys[2] = ~0ull;
        }
    }
}

// K2: resolve multi-assigned anchors -> single bit = argmax-IoU gt (first max).
__global__ __launch_bounds__(256) void k_multi(const float4* __restrict__ anc,
        const float4* __restrict__ gtb, unsigned int* __restrict__ mask) {
    const int idx = blockIdx.x * 256 + threadIdx.x;
    unsigned int m = mask[idx];
    if (__popc(m) > 1) {
        const int b = idx / A_TOT;
        const int a = idx - b * A_TOT;
        const float4 A4 = anc[a];
        const float4* gr = gtb + b * NMAX;
        float bestv = -1.0f; int bestg = 0;
        for (int g = 0; g < NMAX; ++g) {
            float v = iou_box(gr[g], A4);
            if (v > bestv) { bestv = v; bestg = g; }
        }
        mask[idx] = 1u << bestg;
    }
}

// K3: per (b,g) threshold = sum/count + sqrt((sum2 - sum^2/A)/(A-1)), double, deterministic.
__global__ __launch_bounds__(256) void k_thresh(const float4* __restrict__ anc,
        const float4* __restrict__ gtb, const unsigned int* __restrict__ mask,
        double* __restrict__ thr) {
    const int bg = blockIdx.x;
    const int b = bg >> 5;
    const unsigned int bitg = 1u << (bg & 31);
    const unsigned int* mrow = mask + (size_t)b * A_TOT;
    const float4 G = gtb[bg];
    double s = 0.0, s2 = 0.0; int c = 0;
    for (int a = threadIdx.x; a < A_TOT; a += 256) {
        if (mrow[a] & bitg) {
            float v = iou_box(G, anc[a]);
            s += (double)v; s2 += (double)v * (double)v; ++c;
        }
    }
    const int lane = threadIdx.x & 63, wv = threadIdx.x >> 6;
#pragma unroll
    for (int off = 32; off > 0; off >>= 1) {
        s  += __shfl_down(s, off);
        s2 += __shfl_down(s2, off);
        c  += __shfl_down(c, off);
    }
    __shared__ double ss[4], ss2[4];
    __shared__ int sc[4];
    if (lane == 0) { ss[wv] = s; ss2[wv] = s2; sc[wv] = c; }
    __syncthreads();
    if (threadIdx.x == 0) {
        double S = ss[0] + ss[1] + ss[2] + ss[3];
        double S2 = ss2[0] + ss2[1] + ss2[2] + ss2[3];
        int C = sc[0] + sc[1] + sc[2] + sc[3];
        double t;
        if (C == 0) t = 1e300;
        else {
            double var = (S2 - S * S / (double)A_TOT) / (double)(A_TOT - 1);
            if (var < 0.0) var = 0.0;
            t = S / (double)C + sqrt(var);
        }
        thr[bg] = t;
    }
}

// K4: single writer of the ENTIRE output. Block owns 256 consecutive anchors;
// zero-fills its own contiguous score chunk (coalesced float4), syncs, scatters
// its positives into its own chunk. No memset of d_out needed.
__global__ __launch_bounds__(256) void k_out(const float4* __restrict__ anc,
        const float4* __restrict__ gtb, const int* __restrict__ glab,
        const float* __restrict__ mgt, const float4* __restrict__ pd,
        const unsigned int* __restrict__ mask, const double* __restrict__ thr,
        float* __restrict__ out) {
    const int idx = blockIdx.x * 256 + threadIdx.x;   // grid exactly 2100*256 = BSZ*A_TOT
    const int b = idx / A_TOT;
    const int a = idx - b * A_TOT;
    const unsigned int m = mask[idx];     // popcount <= 1 after K2
    bool keep = false; int g = 0;
    if (m) {
        g = __ffs(m) - 1;
        const float v = iou_box(gtb[b * NMAX + g], anc[a]);
        keep = ((double)v > thr[b * NMAX + g]) && (mgt[b * NMAX + g] != 0.0f);
    }
    const int ag = keep ? g : 0;          // argmax of all-zero cid -> 0
    const int lab = keep ? glab[b * NMAX + ag] : NCLS;
    out[LAB_OFF + idx] = (float)lab;
    *(float4*)(out + BOX_OFF + (size_t)idx * 4) = gtb[b * NMAX + ag];
    out[POS_OFF + idx] = keep ? 1.0f : 0.0f;
    float mx = 0.0f;
    if (keep) {
        const float4 P = pd[idx];
        const float4* gr = gtb + b * NMAX;
        mx = -INFINITY;
        for (int g2 = 0; g2 < NMAX; ++g2) mx = fmaxf(mx, iou_box(P, gr[g2]));  // iou(pd, gt)
    }
    // zero this block's score chunk: 256 anchors * 80 f32 = 5120 float4, coalesced
    float4* sc4 = (float4*)(out + SC_OFF) + (size_t)blockIdx.x * 5120;
    const float4 z = make_float4(0.f, 0.f, 0.f, 0.f);
#pragma unroll
    for (int k = 0; k < 20; ++k) sc4[threadIdx.x + k * 256] = z;
    __syncthreads();                      // chunk zeroed before intra-block scatter
    if (keep) out[SC_OFF + (size_t)idx * NCLS + lab] = mx;
}

extern "C" void kernel_launch(void* const* d_in, const int* in_sizes, int n_in,
                              void* d_out, int out_size, void* d_ws, size_t ws_size,
                              hipStream_t stream) {
    const float4* anc = (const float4*)d_in[0];
    const int*    glab = (const int*)d_in[2];
    const float4* gtb  = (const float4*)d_in[3];
    const float*  mgt  = (const float*)d_in[4];
    const float4* pd   = (const float4*)d_in[5];
    float* out = (float*)d_out;

    // workspace layout
    unsigned int* mask = (unsigned int*)d_ws;                                // 2,150,400 B
    double* thr = (double*)((char*)d_ws + 2150400);                          //     4,096 B
    unsigned long long* part = (unsigned long long*)((char*)d_ws + 2154496); //   774,144 B

    hipMemsetAsync(mask, 0, (size_t)BSZ * A_TOT * 4, stream);   // only remaining fill (2.15 MB)

    k_topk_part <<<BSZ * NMAX * WPG / 4, 256, 0, stream>>>(anc, gtb, mgt, part);
    k_topk_merge<<<BSZ * NMAX * 3 / 4, 256, 0, stream>>>(part, mask);
    k_multi <<<BSZ * A_TOT / 256, 256, 0, stream>>>(anc, gtb, mask);
    k_thresh<<<BSZ * NMAX, 256, 0, stream>>>(anc, gtb, mask, thr);
    k_out   <<<BSZ * A_TOT / 256, 256, 0, stream>>>(anc, gtb, glab, mgt, pd, mask, thr, out);
}